// Round 2
// baseline (560.679 us; speedup 1.0000x reference)
//
#include <hip/hip_runtime.h>

typedef __attribute__((ext_vector_type(8))) short short8;
typedef __attribute__((ext_vector_type(4))) float v4f;

#define C_CH 128
#define S_SP 16384
#define NSLICE 16
#define KTOT 384

__device__ inline float bf2f(unsigned short u) {
  union { unsigned int i; float f; } v; v.i = ((unsigned int)u) << 16; return v.f;
}
__device__ inline unsigned short f2bf(float f) {
  union { float f; unsigned int i; } v; v.f = f;
  unsigned int u = v.i;
  return (unsigned short)((u + 0x7FFFu + ((u >> 16) & 1u)) >> 16);
}

// ---- weight repack: Wr[o][t*128+c] = bf16(w[o][c][t]); bias fp32 copy --------
__global__ __launch_bounds__(256) void repack_kernel(
    const float* __restrict__ wq, const float* __restrict__ wk,
    const float* __restrict__ wv, const float* __restrict__ wp,
    const float* __restrict__ bq, const float* __restrict__ bk,
    const float* __restrict__ bv, const float* __restrict__ bp,
    unsigned short* __restrict__ Wr, float* __restrict__ biasf)
{
  int i = blockIdx.x * 256 + threadIdx.x;
  const int WN = 4 * 49152;
  if (i < WN) {
    int m = i / 49152;
    int r = i % 49152;
    int o = r / 384, k = r % 384;
    int t = k >> 7, c = k & 127;
    const float* w = (m == 0) ? wq : (m == 1) ? wk : (m == 2) ? wv : wp;
    Wr[i] = f2bf(w[o * 384 + c * 3 + t]);
  } else if (i < WN + 512) {
    int j = i - WN;
    int m = j >> 7, o = j & 127;
    const float* bb = (m == 0) ? bq : (m == 1) ? bk : (m == 2) ? bv : bp;
    biasf[j] = bb[o];
  }
}

// ---- ingress: fp32 [R][C] -> bf16 [C][R], per z-slice (R=128, C=16384) -------
__global__ __launch_bounds__(256) void transpose_f2b_kernel(
    const float* __restrict__ in, unsigned short* __restrict__ out,
    int R, int C)
{
  __shared__ unsigned short t[64][72];
  int tid = threadIdx.x;
  size_t slice = blockIdx.z;
  const float* ip = in + slice * (size_t)R * C;
  unsigned short* op = out + slice * (size_t)R * C;
  int c0 = blockIdx.x * 64, r0 = blockIdx.y * 64;
#pragma unroll
  for (int p = 0; p < 4; ++p) {
    int id = tid + p * 256;
    int row = id >> 4, col = (id & 15) * 4;
    float4 v = *(const float4*)(ip + (size_t)(r0 + row) * C + c0 + col);
    t[row][col + 0] = f2bf(v.x);
    t[row][col + 1] = f2bf(v.y);
    t[row][col + 2] = f2bf(v.z);
    t[row][col + 3] = f2bf(v.w);
  }
  __syncthreads();
#pragma unroll
  for (int p = 0; p < 2; ++p) {
    int id = tid + p * 256;
    int crow = id >> 3, rcol = (id & 7) * 8;
    uint4 v;
    v.x = (unsigned)t[rcol + 0][crow] | ((unsigned)t[rcol + 1][crow] << 16);
    v.y = (unsigned)t[rcol + 2][crow] | ((unsigned)t[rcol + 3][crow] << 16);
    v.z = (unsigned)t[rcol + 4][crow] | ((unsigned)t[rcol + 5][crow] << 16);
    v.w = (unsigned)t[rcol + 6][crow] | ((unsigned)t[rcol + 7][crow] << 16);
    *(uint4*)(op + (size_t)(c0 + crow) * R + r0 + rcol) = v;
  }
}

// ---- egress: bf16 [R][C] -> fp32 [C][R], per z-slice (R=16384, C=128) --------
__global__ __launch_bounds__(256) void transpose_b2f_kernel(
    const unsigned short* __restrict__ in, float* __restrict__ out,
    int R, int C)
{
  __shared__ unsigned short t[64][72];
  int tid = threadIdx.x;
  size_t slice = blockIdx.z;
  const unsigned short* ip = in + slice * (size_t)R * C;
  float* op = out + slice * (size_t)R * C;
  int c0 = blockIdx.x * 64, r0 = blockIdx.y * 64;
#pragma unroll
  for (int p = 0; p < 2; ++p) {
    int id = tid + p * 256;
    int row = id >> 3, col = (id & 7) * 8;
    uint4 v = *(const uint4*)(ip + (size_t)(r0 + row) * C + c0 + col);
    *(uint4*)(&t[row][col]) = v;
  }
  __syncthreads();
#pragma unroll
  for (int p = 0; p < 4; ++p) {
    int id = tid + p * 256;
    int crow = id >> 4, rcol = (id & 15) * 4;
    float4 v;
    v.x = bf2f(t[rcol + 0][crow]);
    v.y = bf2f(t[rcol + 1][crow]);
    v.z = bf2f(t[rcol + 2][crow]);
    v.w = bf2f(t[rcol + 3][crow]);
    *(float4*)(op + (size_t)(c0 + crow) * R + r0 + rcol) = v;
  }
}

// ---- MFMA conv: out[slice][s][o] = bias[o] + sum_k Wr[o,k]*Xc[s,k] -----------
// Xc[s, t*128+c] = inT[b, l-1+t, s, c] (zero outside the 4-slice half)
__global__ __launch_bounds__(256) void conv_mfma_kernel(
    const unsigned short* __restrict__ inT,
    const unsigned short* __restrict__ Wr_all,
    const float* __restrict__ bias_all,
    unsigned short* __restrict__ outT_all)
{
  __shared__ unsigned short Alds[128 * 40];  // [o][32k] pitch 40 (+8 pad)
  __shared__ unsigned short Blds[128 * 40];  // [s][32k]
  int z = blockIdx.z;
  const unsigned short* Wr = Wr_all + (size_t)z * 49152;
  const float* bias = bias_all + z * 128;
  unsigned short* outT = outT_all + (size_t)z * NSLICE * S_SP * C_CH;

  int tid = threadIdx.x;
  int s0 = blockIdx.x * 128;
  int slice = blockIdx.y;
  int b = slice >> 3, l = slice & 7;
  int half = l >> 2;
  int wave = tid >> 6, lane = tid & 63;
  int wm = wave >> 1, wn = wave & 1;
  int quad = lane >> 4, l15 = lane & 15;

  v4f acc[4][4];
#pragma unroll
  for (int i = 0; i < 4; ++i)
#pragma unroll
    for (int j = 0; j < 4; ++j)
      acc[i][j] = (v4f){0.f, 0.f, 0.f, 0.f};

  for (int step = 0; step < 12; ++step) {
    int t = step >> 2;
    int c0 = (step & 3) * 32;
    int lp = l - 1 + t;
    bool valid = (lp >= half * 4) && (lp <= half * 4 + 3);
    int lpc = valid ? lp : half * 4;  // clamped; loads masked by `valid`
    const unsigned short* bsrc =
        inT + ((size_t)(b * 8 + lpc) * S_SP + s0) * C_CH + c0;
    __syncthreads();
#pragma unroll
    for (int p = 0; p < 2; ++p) {
      int id = tid + p * 256;
      int row = id >> 2, col = (id & 3) * 8;
      uint4 va = *(const uint4*)(Wr + row * KTOT + step * 32 + col);
      *(uint4*)(Alds + row * 40 + col) = va;
      uint4 vb; vb.x = 0; vb.y = 0; vb.z = 0; vb.w = 0;
      if (valid) vb = *(const uint4*)(bsrc + (size_t)row * C_CH + col);
      *(uint4*)(Blds + row * 40 + col) = vb;
    }
    __syncthreads();
    short8 af[4], bfr[4];
#pragma unroll
    for (int i = 0; i < 4; ++i)
      af[i] = *(const short8*)(Alds + (wm * 64 + i * 16 + l15) * 40 + quad * 8);
#pragma unroll
    for (int j = 0; j < 4; ++j)
      bfr[j] = *(const short8*)(Blds + (wn * 64 + j * 16 + l15) * 40 + quad * 8);
#pragma unroll
    for (int i = 0; i < 4; ++i)
#pragma unroll
      for (int j = 0; j < 4; ++j)
        acc[i][j] = __builtin_amdgcn_mfma_f32_16x16x32_bf16(af[i], bfr[j], acc[i][j], 0, 0, 0);
  }

#pragma unroll
  for (int i = 0; i < 4; ++i) {
    int obase = wm * 64 + i * 16 + quad * 4;
    float4 bb = *(const float4*)(bias + obase);
#pragma unroll
    for (int j = 0; j < 4; ++j) {
      int s = s0 + wn * 64 + j * 16 + l15;
      float f0 = acc[i][j].x + bb.x;
      float f1 = acc[i][j].y + bb.y;
      float f2 = acc[i][j].z + bb.z;
      float f3 = acc[i][j].w + bb.w;
      uint2 st;
      st.x = (unsigned)f2bf(f0) | ((unsigned)f2bf(f1) << 16);
      st.y = (unsigned)f2bf(f2) | ((unsigned)f2bf(f3) << 16);
      *(uint2*)(outT + ((size_t)slice * S_SP + s) * C_CH + obase) = st;
    }
  }
}

// ---- fused both-direction window attention -----------------------------------
__device__ inline void load16(const unsigned short* p, float* f) {
  uint4 a = *(const uint4*)p;
  uint4 c = *(const uint4*)(p + 8);
  unsigned v[8] = {a.x, a.y, a.z, a.w, c.x, c.y, c.z, c.w};
#pragma unroll
  for (int i = 0; i < 8; ++i) {
    f[2 * i] = bf2f((unsigned short)(v[i] & 0xffffu));
    f[2 * i + 1] = bf2f((unsigned short)(v[i] >> 16));
  }
}

__global__ __launch_bounds__(256) void attn_kernel(
    const unsigned short* __restrict__ QT,
    const unsigned short* __restrict__ KT,
    const unsigned short* __restrict__ VT,
    unsigned short* __restrict__ YT)
{
  int tid = threadIdx.x;
  int wave = tid >> 6, lane = tid & 63;
  int dir = wave & 1;
  int win = blockIdx.x * 2 + (wave >> 1);
  int by = blockIdx.y;
  int b = by >> 2, l0 = by & 3;
  int head = lane >> 3, qi = lane & 7;
  int d0 = win >> 8, h0 = (win >> 4) & 15, w0 = win & 15;
  int lq = l0 + dir * 4;
  int lk = l0 + 4 - dir * 4;
  int sE[8];
#pragma unroll
  for (int e = 0; e < 8; ++e)
    sE[e] = (2 * d0 + (e >> 2)) * 1024 + (2 * h0 + ((e >> 1) & 1)) * 32 + (2 * w0 + (e & 1));

  size_t qbase = ((size_t)(b * 8 + lq) * S_SP + sE[qi]) * C_CH + head * 16;
  size_t kslice = (size_t)(b * 8 + lk) * S_SP;
  float q[16];
  load16(QT + qbase, q);

  float lg[8];
#pragma unroll
  for (int j = 0; j < 8; ++j) {
    float kk[16];
    load16(KT + (kslice + sE[j]) * C_CH + head * 16, kk);
    float d = 0.f;
#pragma unroll
    for (int x = 0; x < 16; ++x) d += q[x] * kk[x];
    lg[j] = d * 0.25f;  // scale = (C/NH)^-0.5 = 1/4
  }
  float m = lg[0];
#pragma unroll
  for (int j = 1; j < 8; ++j) m = fmaxf(m, lg[j]);
  float p[8], sum = 0.f;
#pragma unroll
  for (int j = 0; j < 8; ++j) { p[j] = __expf(lg[j] - m); sum += p[j]; }
  float inv = 1.0f / sum;

  float y[16];
#pragma unroll
  for (int x = 0; x < 16; ++x) y[x] = 0.f;
#pragma unroll
  for (int j = 0; j < 8; ++j) {
    float vv[16];
    load16(VT + (kslice + sE[j]) * C_CH + head * 16, vv);
    float pj = p[j] * inv;
#pragma unroll
    for (int x = 0; x < 16; ++x) y[x] += pj * vv[x];
  }
  uint4 o0, o1;
  o0.x = (unsigned)f2bf(y[0]) | ((unsigned)f2bf(y[1]) << 16);
  o0.y = (unsigned)f2bf(y[2]) | ((unsigned)f2bf(y[3]) << 16);
  o0.z = (unsigned)f2bf(y[4]) | ((unsigned)f2bf(y[5]) << 16);
  o0.w = (unsigned)f2bf(y[6]) | ((unsigned)f2bf(y[7]) << 16);
  o1.x = (unsigned)f2bf(y[8]) | ((unsigned)f2bf(y[9]) << 16);
  o1.y = (unsigned)f2bf(y[10]) | ((unsigned)f2bf(y[11]) << 16);
  o1.z = (unsigned)f2bf(y[12]) | ((unsigned)f2bf(y[13]) << 16);
  o1.w = (unsigned)f2bf(y[14]) | ((unsigned)f2bf(y[15]) << 16);
  *(uint4*)(YT + qbase) = o0;
  *(uint4*)(YT + qbase + 8) = o1;
}

// -------------------------------------------------------------------------------
extern "C" void kernel_launch(void* const* d_in, const int* in_sizes, int n_in,
                              void* d_out, int out_size, void* d_ws, size_t ws_size,
                              hipStream_t stream) {
  const float* x  = (const float*)d_in[0];
  const float* wq = (const float*)d_in[1];
  const float* bq = (const float*)d_in[2];
  const float* wk = (const float*)d_in[3];
  const float* bk = (const float*)d_in[4];
  const float* wv = (const float*)d_in[5];
  const float* bv = (const float*)d_in[6];
  const float* wp = (const float*)d_in[7];
  const float* bp = (const float*)d_in[8];

  char* ws = (char*)d_ws;
  unsigned short* Wr = (unsigned short*)ws;       // 4*49152 bf16 = 393216 B
  float* biasf = (float*)(ws + 393216);           // 4*128 f32   = 2048 B
  size_t off = 395264;
  const size_t TENB = (size_t)NSLICE * S_SP * C_CH * 2;  // 67108864 B per tensor
  unsigned short* xT = (unsigned short*)(ws + off); off += TENB;
  unsigned short* QT = (unsigned short*)(ws + off); off += TENB;
  unsigned short* KT = (unsigned short*)(ws + off); off += TENB;
  unsigned short* VT = (unsigned short*)(ws + off); off += TENB;
  unsigned short* YT = xT;  // xT dead after QKV convs; reuse for attention out
  unsigned short* OT = QT;  // QT dead after attention; reuse for conv_p output

  // 1) repack weights / biases (fp32 -> bf16 / fp32)
  hipLaunchKernelGGL(repack_kernel, dim3(770), dim3(256), 0, stream,
                     wq, wk, wv, wp, bq, bk, bv, bp, Wr, biasf);
  // 2) x fp32 [c][s] -> xT bf16 [s][c]
  hipLaunchKernelGGL(transpose_f2b_kernel, dim3(256, 2, 16), dim3(256), 0, stream,
                     x, xT, 128, 16384);
  // 3) Q,K,V convs (z selects weights/output; Q,K,V contiguous in ws)
  hipLaunchKernelGGL(conv_mfma_kernel, dim3(128, 16, 3), dim3(256), 0, stream,
                     xT, Wr, biasf, QT);
  // 4) fused both-direction window attention -> YT
  hipLaunchKernelGGL(attn_kernel, dim3(1024, 8), dim3(256), 0, stream,
                     QT, KT, VT, YT);
  // 5) projection conv
  hipLaunchKernelGGL(conv_mfma_kernel, dim3(128, 16, 1), dim3(256), 0, stream,
                     YT, Wr + 3 * 49152, biasf + 384, OT);
  // 6) OT bf16 [s][o] -> d_out fp32 [o][s]
  hipLaunchKernelGGL(transpose_b2f_kernel, dim3(2, 256, 16), dim3(256), 0, stream,
                     OT, (float*)d_out, 16384, 128);
}